// Round 1
// baseline (378.925 us; speedup 1.0000x reference)
//
#include <hip/hip_runtime.h>
#include <math.h>

#define SIGMA_C   1e-4f
#define GAMMA_C   1e-4f
#define ZNEAR_C   1.0f
#define ZFAR_C    100.0f
#define EPSB_C    1e-10f
// compile-time-folded reciprocals (exact constant folding; avoids 10-instr f32 divides)
#define INV_SIGMA  (1.0f / SIGMA_C)
#define INV_GAMMA  (1.0f / GAMMA_C)
#define INV_ZRANGE (1.0f / (ZFAR_C - ZNEAR_C))

static constexpr int N_ = 8, H_ = 512, W_ = 512, K_ = 4;
static constexpr int NPIX = N_ * H_ * W_;     // 2,097,152
static constexpr int NSMP = NPIX * K_;        // 8,388,608
static constexpr int F_ = 100000;
static constexpr int REC_U = 16;              // uints per record (64 B stride, 64B-aligned)
static constexpr size_t TABLE_BYTES = (size_t)F_ * REC_U * sizeof(unsigned int); // 6.4 MB

typedef float        fvec4 __attribute__((ext_vector_type(4)));
typedef float        fvec2 __attribute__((ext_vector_type(2)));
typedef unsigned int uvec4 __attribute__((ext_vector_type(4)));
typedef unsigned int uvec2 __attribute__((ext_vector_type(2)));
typedef _Float16     hvec2 __attribute__((ext_vector_type(2)));

struct F3 { float x, y, z; };

__device__ __forceinline__ float ntf(const float* p) {
    return __builtin_nontemporal_load(p);
}
__device__ __forceinline__ unsigned int packh(float lo, float hi) {
    hvec2 h; h.x = (_Float16)lo; h.y = (_Float16)hi;
    return __builtin_bit_cast(unsigned int, h);
}
__device__ __forceinline__ hvec2 unpackh(unsigned int u) {
    return __builtin_bit_cast(hvec2, u);
}

// Quad (4-lane) cross-lane via DPP quad_perm — VALU pipe, no LDS round trip.
// Samples of a pixel occupy lanes 4q..4q+3, so xor1/xor2 stay inside a quad.
__device__ __forceinline__ float qxor1(float v) {   // quad_perm:[1,0,3,2] = 0xB1
    return __builtin_bit_cast(float, __builtin_amdgcn_update_dpp(
        0, __builtin_bit_cast(int, v), 0xB1, 0xF, 0xF, true));
}
__device__ __forceinline__ float qxor2(float v) {   // quad_perm:[2,3,0,1] = 0x4E
    return __builtin_bit_cast(float, __builtin_amdgcn_update_dpp(
        0, __builtin_bit_cast(int, v), 0x4E, 0xF, 0xF, true));
}

// Fast approx helpers (v_rcp_f32 / v_rsq_f32: ~1 ulp; fine vs fp16-vert error path)
__device__ __forceinline__ float frcp(float x)  { return __builtin_amdgcn_rcpf(x); }
__device__ __forceinline__ float frsq(float x)  { return __builtin_amdgcn_rsqf(x); }

// ---------------- Phase 1: pack faces -> 64B records --------------------
// rec (16 dwords): [n0.x n0.y n0.z n1.x][n1.y n1.z n2.x n2.y]
//                  [n2.z h(v0x,v0y) h(v0z,v1x) h(v1y,v1z)][h(v2x,v2y) h(v2z,0) pad pad]
// normals fp32 (1/|pn| + ^shininess amplification forbids compression);
// verts fp16 (benign error path). 1 cache line, 4 divergent loads per sample.
__global__ __launch_bounds__(256) void build_face_table(
    const float* __restrict__ verts,
    const float* __restrict__ vnorm,
    const int*   __restrict__ faces,
    unsigned int* __restrict__ table)
{
    const int f = blockIdx.x * 256 + threadIdx.x;
    if (f >= F_) return;
    const int i0 = faces[3*f+0], i1 = faces[3*f+1], i2 = faces[3*f+2];
    const F3 a = reinterpret_cast<const F3*>(verts)[i0];
    const F3 b = reinterpret_cast<const F3*>(verts)[i1];
    const F3 c = reinterpret_cast<const F3*>(verts)[i2];
    const F3 p = reinterpret_cast<const F3*>(vnorm)[i0];
    const F3 q = reinterpret_cast<const F3*>(vnorm)[i1];
    const F3 r = reinterpret_cast<const F3*>(vnorm)[i2];
    unsigned int* o = table + (size_t)f * REC_U;
    fvec4 A; A.x = p.x; A.y = p.y; A.z = p.z; A.w = q.x;
    fvec4 B; B.x = q.y; B.y = q.z; B.z = r.x; B.w = r.y;
    uvec4 C; C.x = __builtin_bit_cast(unsigned int, r.z);
    C.y = packh(a.x, a.y); C.z = packh(a.z, b.x); C.w = packh(b.y, b.z);
    uvec4 D; D.x = packh(c.x, c.y); D.y = packh(c.z, 0.0f); D.z = 0u; D.w = 0u;
    *reinterpret_cast<fvec4*>(o + 0)  = A;
    *reinterpret_cast<fvec4*>(o + 4)  = B;
    *reinterpret_cast<uvec4*>(o + 8)  = C;
    *reinterpret_cast<uvec4*>(o + 12) = D;   // full-width store; pad dwords unused
}

// ---------------- Phase 2: one thread per (pixel, sample) ----------------
__global__ __launch_bounds__(256) void soft_phong_sample(
    const unsigned int* __restrict__ table,
    const float* __restrict__ bary,
    const float* __restrict__ zbuf,
    const float* __restrict__ dists,
    const float* __restrict__ texels,
    const float* __restrict__ vis,
    const float* __restrict__ l_loc,
    const float* __restrict__ l_amb,
    const float* __restrict__ l_dif,
    const float* __restrict__ l_spec,
    const float* __restrict__ cam,
    const float* __restrict__ m_amb,
    const float* __restrict__ m_dif,
    const float* __restrict__ m_spec,
    const float* __restrict__ shininess,
    const int*   __restrict__ p2f,
    float* __restrict__ out)
{
    const int s = blockIdx.x * 256 + threadIdx.x;  // sample index = 4*pixel + k
    const int p = s >> 2;
    const int k = s & 3;
    const int n = s >> 20;                         // batch (wave-uniform)

    // face index first -> gather chain starts ASAP
    const int  f0   = __builtin_nontemporal_load(p2f + s);
    const bool live = f0 >= 0;
    const int  f    = live ? f0 : 0;
    const unsigned int* rec = table + (size_t)f * REC_U;
    const fvec4 A = *reinterpret_cast<const fvec4*>(rec + 0);
    const fvec4 B = *reinterpret_cast<const fvec4*>(rec + 4);
    const uvec4 C = *reinterpret_cast<const uvec4*>(rec + 8);
    const uvec2 D = *reinterpret_cast<const uvec2*>(rec + 12);

    // streaming loads (all coalesced dwords across the wave)
    const float zb = ntf(zbuf + s);
    const float dd = ntf(dists + s);
    const float b0 = ntf(bary + 3*s+0), b1 = ntf(bary + 3*s+1), b2 = ntf(bary + 3*s+2);
    const float t0 = ntf(texels + 3*s+0), t1 = ntf(texels + 3*s+1), t2 = ntf(texels + 3*s+2);
    const float vR = vis[3*p+0], vG = vis[3*p+1], vB = vis[3*p+2];

    // per-batch uniforms (wave-uniform -> scalar)
    const float llx = l_loc[3*n+0], lly = l_loc[3*n+1], llz = l_loc[3*n+2];
    const float ccx = cam[3*n+0],   ccy = cam[3*n+1],   ccz = cam[3*n+2];
    const float ambR = m_amb[3*n+0]*l_amb[3*n+0];
    const float ambG = m_amb[3*n+1]*l_amb[3*n+1];
    const float ambB = m_amb[3*n+2]*l_amb[3*n+2];
    const float kdR  = m_dif[3*n+0]*l_dif[3*n+0];
    const float kdG  = m_dif[3*n+1]*l_dif[3*n+1];
    const float kdB  = m_dif[3*n+2]*l_dif[3*n+2];
    const float ksR  = m_spec[3*n+0]*l_spec[3*n+0];
    const float ksG  = m_spec[3*n+1]*l_spec[3*n+1];
    const float ksB  = m_spec[3*n+2]*l_spec[3*n+2];
    const float shin = shininess[n];

    // ---- unpack record ----
    const float n2z = __builtin_bit_cast(float, C.x);
    const hvec2 h0 = unpackh(C.y);   // v0x v0y
    const hvec2 h1 = unpackh(C.z);   // v0z v1x
    const hvec2 h2 = unpackh(C.w);   // v1y v1z
    const hvec2 h3 = unpackh(D.x);   // v2x v2y
    const hvec2 h4 = unpackh(D.y);   // v2z -
    const float v0x = (float)h0.x, v0y = (float)h0.y, v0z = (float)h1.x;
    const float v1x = (float)h1.y, v1y = (float)h2.x, v1z = (float)h2.y;
    const float v2x = (float)h3.x, v2y = (float)h3.y, v2z = (float)h4.x;

    // ---- shade this sample ----
    const float pcx = b0*v0x + b1*v1x + b2*v2x;
    const float pcy = b0*v0y + b1*v1y + b2*v2y;
    const float pcz = b0*v0z + b1*v1z + b2*v2z;

    const float pnx = b0*A.x + b1*A.w + b2*B.z;
    const float pny = b0*A.y + b1*B.x + b2*B.w;
    const float pnz = b0*A.z + b1*B.y + b2*n2z;

    // rsqrt on squared length == 1/max(|pn|,1e-6) for |pn| > 1e-6 (guard via 1e-12 on sq)
    const float inl = frsq(fmaxf(pnx*pnx + pny*pny + pnz*pnz, 1e-12f));
    const float nx = pnx*inl, ny = pny*inl, nz = pnz*inl;

    float dx = llx - pcx, dy = lly - pcy, dz = llz - pcz;
    const float idl = frsq(fmaxf(dx*dx + dy*dy + dz*dz, 1e-12f));
    dx *= idl; dy *= idl; dz *= idl;

    const float cosang = nx*dx + ny*dy + nz*dz;
    const float rcos   = fmaxf(cosang, 0.0f);

    const float rx = 2.0f*cosang*nx - dx;
    const float ry = 2.0f*cosang*ny - dy;
    const float rz = 2.0f*cosang*nz - dz;

    float vx = ccx - pcx, vy = ccy - pcy, vz = ccz - pcz;
    const float ivl = frsq(fmaxf(vx*vx + vy*vy + vz*vz, 1e-12f));
    vx *= ivl; vy *= ivl; vz *= ivl;

    const float sdot = vx*rx + vy*ry + vz*rz;
    const float spec_cos = (cosang > 0.0f) ? fmaxf(sdot, 0.0f) : 0.0f;
    const float sp = (spec_cos > 0.0f) ? exp2f(shin * log2f(spec_cos)) : 0.0f;

    const float colR = (ambR + kdR*rcos*vR) * t0 + ksR*sp;
    const float colG = (ambG + kdG*rcos*vG) * t1 + ksG*sp;
    const float colB = (ambB + kdB*rcos*vB) * t2 + ksB*sp;

    const float prob = live ? frcp(1.0f + __expf(dd * INV_SIGMA)) : 0.0f;
    const float zinv = live ? (ZFAR_C - zb) * INV_ZRANGE : 0.0f;

    // ---- quad (4-lane) blend reduction via DPP butterflies (no LDS) ----
    float zmax = zinv;
    zmax = fmaxf(zmax, qxor1(zmax));
    zmax = fmaxf(zmax, qxor2(zmax));
    zmax = fmaxf(zmax, EPSB_C);

    const float w = prob * __expf((zinv - zmax) * INV_GAMMA);
    float aw = w, aR = w*colR, aG = w*colG, aB = w*colB, kp = 1.0f - prob;

    aw += qxor1(aw);  aR += qxor1(aR);
    aG += qxor1(aG);  aB += qxor1(aB);
    kp *= qxor1(kp);
    aw += qxor2(aw);  aR += qxor2(aR);
    aG += qxor2(aG);  aB += qxor2(aB);
    kp *= qxor2(kp);

    const float delta = __expf((EPSB_C - zmax) * INV_GAMMA);
    const float inv   = frcp(aw + delta);

    // lane k writes channel k -> out[4p+k] == out[s]; fully coalesced dwords
    float val;
    if      (k == 0) val = (aR + delta) * inv;
    else if (k == 1) val = (aG + delta) * inv;
    else if (k == 2) val = (aB + delta) * inv;
    else             val = 1.0f - kp;
    __builtin_nontemporal_store(val, out + s);
}

// ---------------- Fallback (direct per-pixel gather) --------------------
__global__ __launch_bounds__(256) void soft_phong_direct(
    const float* __restrict__ verts,
    const float* __restrict__ vnorm,
    const float* __restrict__ bary,
    const float* __restrict__ zbuf,
    const float* __restrict__ dists,
    const float* __restrict__ texels,
    const float* __restrict__ vis,
    const float* __restrict__ l_loc,
    const float* __restrict__ l_amb,
    const float* __restrict__ l_dif,
    const float* __restrict__ l_spec,
    const float* __restrict__ cam,
    const float* __restrict__ m_amb,
    const float* __restrict__ m_dif,
    const float* __restrict__ m_spec,
    const float* __restrict__ shininess,
    const int*   __restrict__ faces,
    const int*   __restrict__ p2f,
    float* __restrict__ out)
{
    const int p = blockIdx.x * 256 + threadIdx.x;
    const int n = p >> 18;
    struct I3 { int x, y, z; };
    const int fi[4] = {p2f[4*p+0], p2f[4*p+1], p2f[4*p+2], p2f[4*p+3]};
    I3 fidx[4];
#pragma unroll
    for (int k = 0; k < 4; ++k) {
        const int f = (fi[k] >= 0) ? fi[k] : 0;
        fidx[k] = reinterpret_cast<const I3*>(faces)[f];
    }
    F3 vp[4][3], vn[4][3];
#pragma unroll
    for (int k = 0; k < 4; ++k) {
        const int i0 = fidx[k].x, i1 = fidx[k].y, i2 = fidx[k].z;
        vp[k][0] = reinterpret_cast<const F3*>(verts)[i0];
        vp[k][1] = reinterpret_cast<const F3*>(verts)[i1];
        vp[k][2] = reinterpret_cast<const F3*>(verts)[i2];
        vn[k][0] = reinterpret_cast<const F3*>(vnorm)[i0];
        vn[k][1] = reinterpret_cast<const F3*>(vnorm)[i1];
        vn[k][2] = reinterpret_cast<const F3*>(vnorm)[i2];
    }
    const float llx = l_loc[3*n+0], lly = l_loc[3*n+1], llz = l_loc[3*n+2];
    const float ccx = cam[3*n+0],   ccy = cam[3*n+1],   ccz = cam[3*n+2];
    const float ambR = m_amb[3*n+0]*l_amb[3*n+0];
    const float ambG = m_amb[3*n+1]*l_amb[3*n+1];
    const float ambB = m_amb[3*n+2]*l_amb[3*n+2];
    const float kdR  = m_dif[3*n+0]*l_dif[3*n+0];
    const float kdG  = m_dif[3*n+1]*l_dif[3*n+1];
    const float kdB  = m_dif[3*n+2]*l_dif[3*n+2];
    const float ksR  = m_spec[3*n+0]*l_spec[3*n+0];
    const float ksG  = m_spec[3*n+1]*l_spec[3*n+1];
    const float ksB  = m_spec[3*n+2]*l_spec[3*n+2];
    const float shin = shininess[n];
    float colR[4], colG[4], colB[4], prob[4], zinv[4];
    float zmax = EPSB_C;
#pragma unroll
    for (int k = 0; k < 4; ++k) {
        const bool live = fi[k] >= 0;
        const float b0 = bary[12*p+3*k+0], b1 = bary[12*p+3*k+1], b2 = bary[12*p+3*k+2];
        const float pcx = b0*vp[k][0].x + b1*vp[k][1].x + b2*vp[k][2].x;
        const float pcy = b0*vp[k][0].y + b1*vp[k][1].y + b2*vp[k][2].y;
        const float pcz = b0*vp[k][0].z + b1*vp[k][1].z + b2*vp[k][2].z;
        const float pnx = b0*vn[k][0].x + b1*vn[k][1].x + b2*vn[k][2].x;
        const float pny = b0*vn[k][0].y + b1*vn[k][1].y + b2*vn[k][2].y;
        const float pnz = b0*vn[k][0].z + b1*vn[k][1].z + b2*vn[k][2].z;
        const float inl = frsq(fmaxf(pnx*pnx + pny*pny + pnz*pnz, 1e-12f));
        const float nx = pnx*inl, ny = pny*inl, nz = pnz*inl;
        float dx = llx - pcx, dy = lly - pcy, dz = llz - pcz;
        const float idl = frsq(fmaxf(dx*dx + dy*dy + dz*dz, 1e-12f));
        dx *= idl; dy *= idl; dz *= idl;
        const float cosang = nx*dx + ny*dy + nz*dz;
        const float rcos   = fmaxf(cosang, 0.0f);
        const float rx = 2.0f*cosang*nx - dx;
        const float ry = 2.0f*cosang*ny - dy;
        const float rz = 2.0f*cosang*nz - dz;
        float vx = ccx - pcx, vy = ccy - pcy, vz = ccz - pcz;
        const float ivl = frsq(fmaxf(vx*vx + vy*vy + vz*vz, 1e-12f));
        vx *= ivl; vy *= ivl; vz *= ivl;
        const float sdot = vx*rx + vy*ry + vz*rz;
        const float spec_cos = (cosang > 0.0f) ? fmaxf(sdot, 0.0f) : 0.0f;
        const float sp = (spec_cos > 0.0f) ? exp2f(shin * log2f(spec_cos)) : 0.0f;
        const float vRl = vis[3*p+0], vGl = vis[3*p+1], vBl = vis[3*p+2];
        colR[k] = (ambR + kdR*rcos*vRl) * texels[12*p+3*k+0] + ksR*sp;
        colG[k] = (ambG + kdG*rcos*vGl) * texels[12*p+3*k+1] + ksG*sp;
        colB[k] = (ambB + kdB*rcos*vBl) * texels[12*p+3*k+2] + ksB*sp;
        prob[k] = live ? frcp(1.0f + __expf(dists[4*p+k] * INV_SIGMA)) : 0.0f;
        zinv[k] = live ? (ZFAR_C - zbuf[4*p+k]) * INV_ZRANGE : 0.0f;
        zmax = fmaxf(zmax, zinv[k]);
    }
    const float delta = __expf((EPSB_C - zmax) * INV_GAMMA);
    float denom = delta, accR = delta, accG = delta, accB = delta, keep = 1.0f;
#pragma unroll
    for (int k = 0; k < 4; ++k) {
        const float w = prob[k] * __expf((zinv[k] - zmax) * INV_GAMMA);
        denom += w; accR += w*colR[k]; accG += w*colG[k]; accB += w*colB[k];
        keep *= (1.0f - prob[k]);
    }
    const float inv = frcp(denom);
    out[4*p+0] = accR*inv; out[4*p+1] = accG*inv; out[4*p+2] = accB*inv; out[4*p+3] = 1.0f - keep;
}

extern "C" void kernel_launch(void* const* d_in, const int* in_sizes, int n_in,
                              void* d_out, int out_size, void* d_ws, size_t ws_size,
                              hipStream_t stream) {
    const float* verts   = (const float*)d_in[0];
    const float* vnorm   = (const float*)d_in[1];
    const float* bary    = (const float*)d_in[2];
    const float* zbuf    = (const float*)d_in[3];
    const float* dists   = (const float*)d_in[4];
    const float* texels  = (const float*)d_in[5];
    const float* vis     = (const float*)d_in[6];
    const float* l_loc   = (const float*)d_in[7];
    const float* l_amb   = (const float*)d_in[8];
    const float* l_dif   = (const float*)d_in[9];
    const float* l_spec  = (const float*)d_in[10];
    const float* cam     = (const float*)d_in[11];
    const float* m_amb   = (const float*)d_in[12];
    const float* m_dif   = (const float*)d_in[13];
    const float* m_spec  = (const float*)d_in[14];
    const float* shin    = (const float*)d_in[15];
    const int*   faces   = (const int*)d_in[16];
    const int*   p2f     = (const int*)d_in[17];
    float* out = (float*)d_out;

    if (ws_size >= TABLE_BYTES) {
        unsigned int* table = (unsigned int*)d_ws;
        build_face_table<<<(F_ + 255) / 256, 256, 0, stream>>>(verts, vnorm, faces, table);
        soft_phong_sample<<<NSMP / 256, 256, 0, stream>>>(
            table, bary, zbuf, dists, texels, vis,
            l_loc, l_amb, l_dif, l_spec, cam,
            m_amb, m_dif, m_spec, shin, p2f, out);
    } else {
        soft_phong_direct<<<NPIX / 256, 256, 0, stream>>>(
            verts, vnorm, bary, zbuf, dists, texels, vis,
            l_loc, l_amb, l_dif, l_spec, cam,
            m_amb, m_dif, m_spec, shin, faces, p2f, out);
    }
}

// Round 2
// 359.671 us; speedup vs baseline: 1.0535x; 1.0535x over previous
//
#include <hip/hip_runtime.h>
#include <math.h>

#define SIGMA_C   1e-4f
#define GAMMA_C   1e-4f
#define ZNEAR_C   1.0f
#define ZFAR_C    100.0f
#define EPSB_C    1e-10f
// compile-time-folded reciprocals (exact constant folding; avoids 10-instr f32 divides)
#define INV_SIGMA  (1.0f / SIGMA_C)
#define INV_GAMMA  (1.0f / GAMMA_C)
#define INV_ZRANGE (1.0f / (ZFAR_C - ZNEAR_C))

static constexpr int N_ = 8, H_ = 512, W_ = 512, K_ = 4;
static constexpr int NPIX = N_ * H_ * W_;     // 2,097,152
static constexpr int NSMP = NPIX * K_;        // 8,388,608
static constexpr int F_ = 100000;
static constexpr int REC_U = 16;              // uints per record (64 B stride, 64B-aligned)
static constexpr size_t TABLE_BYTES = (size_t)F_ * REC_U * sizeof(unsigned int); // 6.4 MB
// blocks per batch for the sample kernel: (H*W*K)/256 = 4096 = 2^12
static_assert((H_ * W_ * K_) / 256 == 4096, "uniform-n derivation");

typedef float        fvec4 __attribute__((ext_vector_type(4)));
typedef float        fvec2 __attribute__((ext_vector_type(2)));
typedef unsigned int uvec4 __attribute__((ext_vector_type(4)));
typedef unsigned int uvec2 __attribute__((ext_vector_type(2)));
typedef _Float16     hvec2 __attribute__((ext_vector_type(2)));
// 12-byte vector with 4B alignment: emits global_load_dwordx3, never widens to 16B
typedef float        fvec3_ __attribute__((ext_vector_type(3)));
typedef fvec3_       fvec3 __attribute__((aligned(4)));

struct F3 { float x, y, z; };

__device__ __forceinline__ float ntf(const float* p) {
    return __builtin_nontemporal_load(p);
}
__device__ __forceinline__ fvec3_ ntf3(const float* p) {
    return __builtin_nontemporal_load(reinterpret_cast<const fvec3*>(p));
}
__device__ __forceinline__ unsigned int packh(float lo, float hi) {
    hvec2 h; h.x = (_Float16)lo; h.y = (_Float16)hi;
    return __builtin_bit_cast(unsigned int, h);
}
__device__ __forceinline__ hvec2 unpackh(unsigned int u) {
    return __builtin_bit_cast(hvec2, u);
}

// Quad (4-lane) cross-lane via DPP quad_perm — VALU pipe, no LDS round trip.
__device__ __forceinline__ float qxor1(float v) {   // quad_perm:[1,0,3,2] = 0xB1
    return __builtin_bit_cast(float, __builtin_amdgcn_update_dpp(
        0, __builtin_bit_cast(int, v), 0xB1, 0xF, 0xF, true));
}
__device__ __forceinline__ float qxor2(float v) {   // quad_perm:[2,3,0,1] = 0x4E
    return __builtin_bit_cast(float, __builtin_amdgcn_update_dpp(
        0, __builtin_bit_cast(int, v), 0x4E, 0xF, 0xF, true));
}
// quad broadcasts: every lane of the quad reads lane {0,1,2}
__device__ __forceinline__ float qbc0(float v) {    // quad_perm:[0,0,0,0] = 0x00
    return __builtin_bit_cast(float, __builtin_amdgcn_update_dpp(
        0, __builtin_bit_cast(int, v), 0x00, 0xF, 0xF, true));
}
__device__ __forceinline__ float qbc1(float v) {    // quad_perm:[1,1,1,1] = 0x55
    return __builtin_bit_cast(float, __builtin_amdgcn_update_dpp(
        0, __builtin_bit_cast(int, v), 0x55, 0xF, 0xF, true));
}
__device__ __forceinline__ float qbc2(float v) {    // quad_perm:[2,2,2,2] = 0xAA
    return __builtin_bit_cast(float, __builtin_amdgcn_update_dpp(
        0, __builtin_bit_cast(int, v), 0xAA, 0xF, 0xF, true));
}

// Fast approx helpers (v_rcp_f32 / v_rsq_f32: ~1 ulp; fine vs fp16-vert error path)
__device__ __forceinline__ float frcp(float x)  { return __builtin_amdgcn_rcpf(x); }
__device__ __forceinline__ float frsq(float x)  { return __builtin_amdgcn_rsqf(x); }

// ---------------- Phase 1: pack faces -> 64B records --------------------
// rec (16 dwords): [n0.x n0.y n0.z n1.x][n1.y n1.z n2.x n2.y]
//                  [n2.z h(v0x,v0y) h(v0z,v1x) h(v1y,v1z)][h(v2x,v2y) h(v2z,0) pad pad]
// normals fp32 (1/|pn| + ^shininess amplification forbids compression);
// verts fp16 (benign error path). 1 cache line, 4 divergent loads per sample.
__global__ __launch_bounds__(256) void build_face_table(
    const float* __restrict__ verts,
    const float* __restrict__ vnorm,
    const int*   __restrict__ faces,
    unsigned int* __restrict__ table)
{
    const int f = blockIdx.x * 256 + threadIdx.x;
    if (f >= F_) return;
    const int i0 = faces[3*f+0], i1 = faces[3*f+1], i2 = faces[3*f+2];
    const F3 a = reinterpret_cast<const F3*>(verts)[i0];
    const F3 b = reinterpret_cast<const F3*>(verts)[i1];
    const F3 c = reinterpret_cast<const F3*>(verts)[i2];
    const F3 p = reinterpret_cast<const F3*>(vnorm)[i0];
    const F3 q = reinterpret_cast<const F3*>(vnorm)[i1];
    const F3 r = reinterpret_cast<const F3*>(vnorm)[i2];
    unsigned int* o = table + (size_t)f * REC_U;
    fvec4 A; A.x = p.x; A.y = p.y; A.z = p.z; A.w = q.x;
    fvec4 B; B.x = q.y; B.y = q.z; B.z = r.x; B.w = r.y;
    uvec4 C; C.x = __builtin_bit_cast(unsigned int, r.z);
    C.y = packh(a.x, a.y); C.z = packh(a.z, b.x); C.w = packh(b.y, b.z);
    uvec4 D; D.x = packh(c.x, c.y); D.y = packh(c.z, 0.0f); D.z = 0u; D.w = 0u;
    *reinterpret_cast<fvec4*>(o + 0)  = A;
    *reinterpret_cast<fvec4*>(o + 4)  = B;
    *reinterpret_cast<uvec4*>(o + 8)  = C;
    *reinterpret_cast<uvec4*>(o + 12) = D;   // full-width store; pad dwords unused
}

// ---------------- Phase 2: one thread per (pixel, sample) ----------------
__global__ __launch_bounds__(256) void soft_phong_sample(
    const unsigned int* __restrict__ table,
    const float* __restrict__ bary,
    const float* __restrict__ zbuf,
    const float* __restrict__ dists,
    const float* __restrict__ texels,
    const float* __restrict__ vis,
    const float* __restrict__ l_loc,
    const float* __restrict__ l_amb,
    const float* __restrict__ l_dif,
    const float* __restrict__ l_spec,
    const float* __restrict__ cam,
    const float* __restrict__ m_amb,
    const float* __restrict__ m_dif,
    const float* __restrict__ m_spec,
    const float* __restrict__ shininess,
    const int*   __restrict__ p2f,
    float* __restrict__ out)
{
    const int s = blockIdx.x * 256 + threadIdx.x;  // sample index = 4*pixel + k
    const int p = s >> 2;
    const int k = s & 3;
    // batch index derived from blockIdx only -> provably wave-uniform -> the 14
    // per-batch loads below become SMEM s_load on the constant cache (not VMEM)
    const int n = blockIdx.x >> 12;                // 4096 blocks per batch

    // face index first -> gather chain starts ASAP
    const int  f0   = __builtin_nontemporal_load(p2f + s);
    const bool live = f0 >= 0;
    const int  f    = live ? f0 : 0;
    const unsigned int* rec = table + (size_t)f * REC_U;
    const fvec4 A = *reinterpret_cast<const fvec4*>(rec + 0);
    const fvec4 B = *reinterpret_cast<const fvec4*>(rec + 4);
    const uvec4 C = *reinterpret_cast<const uvec4*>(rec + 8);
    const uvec2 D = *reinterpret_cast<const uvec2*>(rec + 12);

    // streaming loads (coalesced; dwordx3 where stride-3)
    const float  zb = ntf(zbuf + s);
    const float  dd = ntf(dists + s);
    const fvec3_ bv = ntf3(bary + 3*s);
    const fvec3_ tv = ntf3(texels + 3*s);
    const float b0 = bv.x, b1 = bv.y, b2 = bv.z;
    const float t0 = tv.x, t1 = tv.y, t2 = tv.z;

    // vis: one dword per lane (lane k of the quad loads channel min(k,2)),
    // then quad DPP broadcasts reconstruct all three channels per lane
    const int   kv = (k < 3) ? k : 2;
    const float lv = vis[3*p + kv];
    const float vR = qbc0(lv), vG = qbc1(lv), vB = qbc2(lv);

    // per-batch uniforms (scalarized -> s_load + SALU)
    const float llx = l_loc[3*n+0], lly = l_loc[3*n+1], llz = l_loc[3*n+2];
    const float ccx = cam[3*n+0],   ccy = cam[3*n+1],   ccz = cam[3*n+2];
    const float ambR = m_amb[3*n+0]*l_amb[3*n+0];
    const float ambG = m_amb[3*n+1]*l_amb[3*n+1];
    const float ambB = m_amb[3*n+2]*l_amb[3*n+2];
    const float kdR  = m_dif[3*n+0]*l_dif[3*n+0];
    const float kdG  = m_dif[3*n+1]*l_dif[3*n+1];
    const float kdB  = m_dif[3*n+2]*l_dif[3*n+2];
    const float ksR  = m_spec[3*n+0]*l_spec[3*n+0];
    const float ksG  = m_spec[3*n+1]*l_spec[3*n+1];
    const float ksB  = m_spec[3*n+2]*l_spec[3*n+2];
    const float shin = shininess[n];

    // ---- unpack record ----
    const float n2z = __builtin_bit_cast(float, C.x);
    const hvec2 h0 = unpackh(C.y);   // v0x v0y
    const hvec2 h1 = unpackh(C.z);   // v0z v1x
    const hvec2 h2 = unpackh(C.w);   // v1y v1z
    const hvec2 h3 = unpackh(D.x);   // v2x v2y
    const hvec2 h4 = unpackh(D.y);   // v2z -
    const float v0x = (float)h0.x, v0y = (float)h0.y, v0z = (float)h1.x;
    const float v1x = (float)h1.y, v1y = (float)h2.x, v1z = (float)h2.y;
    const float v2x = (float)h3.x, v2y = (float)h3.y, v2z = (float)h4.x;

    // ---- shade this sample ----
    const float pcx = b0*v0x + b1*v1x + b2*v2x;
    const float pcy = b0*v0y + b1*v1y + b2*v2y;
    const float pcz = b0*v0z + b1*v1z + b2*v2z;

    const float pnx = b0*A.x + b1*A.w + b2*B.z;
    const float pny = b0*A.y + b1*B.x + b2*B.w;
    const float pnz = b0*A.z + b1*B.y + b2*n2z;

    // rsqrt on squared length == 1/max(|pn|,1e-6) for |pn| > 1e-6 (guard via 1e-12 on sq)
    const float inl = frsq(fmaxf(pnx*pnx + pny*pny + pnz*pnz, 1e-12f));
    const float nx = pnx*inl, ny = pny*inl, nz = pnz*inl;

    float dx = llx - pcx, dy = lly - pcy, dz = llz - pcz;
    const float idl = frsq(fmaxf(dx*dx + dy*dy + dz*dz, 1e-12f));
    dx *= idl; dy *= idl; dz *= idl;

    const float cosang = nx*dx + ny*dy + nz*dz;
    const float rcos   = fmaxf(cosang, 0.0f);

    const float rx = 2.0f*cosang*nx - dx;
    const float ry = 2.0f*cosang*ny - dy;
    const float rz = 2.0f*cosang*nz - dz;

    float vx = ccx - pcx, vy = ccy - pcy, vz = ccz - pcz;
    const float ivl = frsq(fmaxf(vx*vx + vy*vy + vz*vz, 1e-12f));
    vx *= ivl; vy *= ivl; vz *= ivl;

    const float sdot = vx*rx + vy*ry + vz*rz;
    const float spec_cos = (cosang > 0.0f) ? fmaxf(sdot, 0.0f) : 0.0f;
    const float sp = (spec_cos > 0.0f) ? exp2f(shin * log2f(spec_cos)) : 0.0f;

    const float colR = (ambR + kdR*rcos*vR) * t0 + ksR*sp;
    const float colG = (ambG + kdG*rcos*vG) * t1 + ksG*sp;
    const float colB = (ambB + kdB*rcos*vB) * t2 + ksB*sp;

    const float prob = live ? frcp(1.0f + __expf(dd * INV_SIGMA)) : 0.0f;
    const float zinv = live ? (ZFAR_C - zb) * INV_ZRANGE : 0.0f;

    // ---- quad (4-lane) blend reduction via DPP butterflies (no LDS) ----
    float zmax = zinv;
    zmax = fmaxf(zmax, qxor1(zmax));
    zmax = fmaxf(zmax, qxor2(zmax));
    zmax = fmaxf(zmax, EPSB_C);

    const float w = prob * __expf((zinv - zmax) * INV_GAMMA);
    float aw = w, aR = w*colR, aG = w*colG, aB = w*colB, kp = 1.0f - prob;

    aw += qxor1(aw);  aR += qxor1(aR);
    aG += qxor1(aG);  aB += qxor1(aB);
    kp *= qxor1(kp);
    aw += qxor2(aw);  aR += qxor2(aR);
    aG += qxor2(aG);  aB += qxor2(aB);
    kp *= qxor2(kp);

    const float delta = __expf((EPSB_C - zmax) * INV_GAMMA);
    const float inv   = frcp(aw + delta);

    // lane k writes channel k -> out[4p+k] == out[s]; fully coalesced dwords
    float val;
    if      (k == 0) val = (aR + delta) * inv;
    else if (k == 1) val = (aG + delta) * inv;
    else if (k == 2) val = (aB + delta) * inv;
    else             val = 1.0f - kp;
    __builtin_nontemporal_store(val, out + s);
}

// ---------------- Fallback (direct per-pixel gather) --------------------
__global__ __launch_bounds__(256) void soft_phong_direct(
    const float* __restrict__ verts,
    const float* __restrict__ vnorm,
    const float* __restrict__ bary,
    const float* __restrict__ zbuf,
    const float* __restrict__ dists,
    const float* __restrict__ texels,
    const float* __restrict__ vis,
    const float* __restrict__ l_loc,
    const float* __restrict__ l_amb,
    const float* __restrict__ l_dif,
    const float* __restrict__ l_spec,
    const float* __restrict__ cam,
    const float* __restrict__ m_amb,
    const float* __restrict__ m_dif,
    const float* __restrict__ m_spec,
    const float* __restrict__ shininess,
    const int*   __restrict__ faces,
    const int*   __restrict__ p2f,
    float* __restrict__ out)
{
    const int p = blockIdx.x * 256 + threadIdx.x;
    const int n = p >> 18;
    struct I3 { int x, y, z; };
    const int fi[4] = {p2f[4*p+0], p2f[4*p+1], p2f[4*p+2], p2f[4*p+3]};
    I3 fidx[4];
#pragma unroll
    for (int k = 0; k < 4; ++k) {
        const int f = (fi[k] >= 0) ? fi[k] : 0;
        fidx[k] = reinterpret_cast<const I3*>(faces)[f];
    }
    F3 vp[4][3], vn[4][3];
#pragma unroll
    for (int k = 0; k < 4; ++k) {
        const int i0 = fidx[k].x, i1 = fidx[k].y, i2 = fidx[k].z;
        vp[k][0] = reinterpret_cast<const F3*>(verts)[i0];
        vp[k][1] = reinterpret_cast<const F3*>(verts)[i1];
        vp[k][2] = reinterpret_cast<const F3*>(verts)[i2];
        vn[k][0] = reinterpret_cast<const F3*>(vnorm)[i0];
        vn[k][1] = reinterpret_cast<const F3*>(vnorm)[i1];
        vn[k][2] = reinterpret_cast<const F3*>(vnorm)[i2];
    }
    const float llx = l_loc[3*n+0], lly = l_loc[3*n+1], llz = l_loc[3*n+2];
    const float ccx = cam[3*n+0],   ccy = cam[3*n+1],   ccz = cam[3*n+2];
    const float ambR = m_amb[3*n+0]*l_amb[3*n+0];
    const float ambG = m_amb[3*n+1]*l_amb[3*n+1];
    const float ambB = m_amb[3*n+2]*l_amb[3*n+2];
    const float kdR  = m_dif[3*n+0]*l_dif[3*n+0];
    const float kdG  = m_dif[3*n+1]*l_dif[3*n+1];
    const float kdB  = m_dif[3*n+2]*l_dif[3*n+2];
    const float ksR  = m_spec[3*n+0]*l_spec[3*n+0];
    const float ksG  = m_spec[3*n+1]*l_spec[3*n+1];
    const float ksB  = m_spec[3*n+2]*l_spec[3*n+2];
    const float shin = shininess[n];
    float colR[4], colG[4], colB[4], prob[4], zinv[4];
    float zmax = EPSB_C;
#pragma unroll
    for (int k = 0; k < 4; ++k) {
        const bool live = fi[k] >= 0;
        const float b0 = bary[12*p+3*k+0], b1 = bary[12*p+3*k+1], b2 = bary[12*p+3*k+2];
        const float pcx = b0*vp[k][0].x + b1*vp[k][1].x + b2*vp[k][2].x;
        const float pcy = b0*vp[k][0].y + b1*vp[k][1].y + b2*vp[k][2].y;
        const float pcz = b0*vp[k][0].z + b1*vp[k][1].z + b2*vp[k][2].z;
        const float pnx = b0*vn[k][0].x + b1*vn[k][1].x + b2*vn[k][2].x;
        const float pny = b0*vn[k][0].y + b1*vn[k][1].y + b2*vn[k][2].y;
        const float pnz = b0*vn[k][0].z + b1*vn[k][1].z + b2*vn[k][2].z;
        const float inl = frsq(fmaxf(pnx*pnx + pny*pny + pnz*pnz, 1e-12f));
        const float nx = pnx*inl, ny = pny*inl, nz = pnz*inl;
        float dx = llx - pcx, dy = lly - pcy, dz = llz - pcz;
        const float idl = frsq(fmaxf(dx*dx + dy*dy + dz*dz, 1e-12f));
        dx *= idl; dy *= idl; dz *= idl;
        const float cosang = nx*dx + ny*dy + nz*dz;
        const float rcos   = fmaxf(cosang, 0.0f);
        const float rx = 2.0f*cosang*nx - dx;
        const float ry = 2.0f*cosang*ny - dy;
        const float rz = 2.0f*cosang*nz - dz;
        float vx = ccx - pcx, vy = ccy - pcy, vz = ccz - pcz;
        const float ivl = frsq(fmaxf(vx*vx + vy*vy + vz*vz, 1e-12f));
        vx *= ivl; vy *= ivl; vz *= ivl;
        const float sdot = vx*rx + vy*ry + vz*rz;
        const float spec_cos = (cosang > 0.0f) ? fmaxf(sdot, 0.0f) : 0.0f;
        const float sp = (spec_cos > 0.0f) ? exp2f(shin * log2f(spec_cos)) : 0.0f;
        const float vRl = vis[3*p+0], vGl = vis[3*p+1], vBl = vis[3*p+2];
        colR[k] = (ambR + kdR*rcos*vRl) * texels[12*p+3*k+0] + ksR*sp;
        colG[k] = (ambG + kdG*rcos*vGl) * texels[12*p+3*k+1] + ksG*sp;
        colB[k] = (ambB + kdB*rcos*vBl) * texels[12*p+3*k+2] + ksB*sp;
        prob[k] = live ? frcp(1.0f + __expf(dists[4*p+k] * INV_SIGMA)) : 0.0f;
        zinv[k] = live ? (ZFAR_C - zbuf[4*p+k]) * INV_ZRANGE : 0.0f;
        zmax = fmaxf(zmax, zinv[k]);
    }
    const float delta = __expf((EPSB_C - zmax) * INV_GAMMA);
    float denom = delta, accR = delta, accG = delta, accB = delta, keep = 1.0f;
#pragma unroll
    for (int k = 0; k < 4; ++k) {
        const float w = prob[k] * __expf((zinv[k] - zmax) * INV_GAMMA);
        denom += w; accR += w*colR[k]; accG += w*colG[k]; accB += w*colB[k];
        keep *= (1.0f - prob[k]);
    }
    const float inv = frcp(denom);
    out[4*p+0] = accR*inv; out[4*p+1] = accG*inv; out[4*p+2] = accB*inv; out[4*p+3] = 1.0f - keep;
}

extern "C" void kernel_launch(void* const* d_in, const int* in_sizes, int n_in,
                              void* d_out, int out_size, void* d_ws, size_t ws_size,
                              hipStream_t stream) {
    const float* verts   = (const float*)d_in[0];
    const float* vnorm   = (const float*)d_in[1];
    const float* bary    = (const float*)d_in[2];
    const float* zbuf    = (const float*)d_in[3];
    const float* dists   = (const float*)d_in[4];
    const float* texels  = (const float*)d_in[5];
    const float* vis     = (const float*)d_in[6];
    const float* l_loc   = (const float*)d_in[7];
    const float* l_amb   = (const float*)d_in[8];
    const float* l_dif   = (const float*)d_in[9];
    const float* l_spec  = (const float*)d_in[10];
    const float* cam     = (const float*)d_in[11];
    const float* m_amb   = (const float*)d_in[12];
    const float* m_dif   = (const float*)d_in[13];
    const float* m_spec  = (const float*)d_in[14];
    const float* shin    = (const float*)d_in[15];
    const int*   faces   = (const int*)d_in[16];
    const int*   p2f     = (const int*)d_in[17];
    float* out = (float*)d_out;

    if (ws_size >= TABLE_BYTES) {
        unsigned int* table = (unsigned int*)d_ws;
        build_face_table<<<(F_ + 255) / 256, 256, 0, stream>>>(verts, vnorm, faces, table);
        soft_phong_sample<<<NSMP / 256, 256, 0, stream>>>(
            table, bary, zbuf, dists, texels, vis,
            l_loc, l_amb, l_dif, l_spec, cam,
            m_amb, m_dif, m_spec, shin, p2f, out);
    } else {
        soft_phong_direct<<<NPIX / 256, 256, 0, stream>>>(
            verts, vnorm, bary, zbuf, dists, texels, vis,
            l_loc, l_amb, l_dif, l_spec, cam,
            m_amb, m_dif, m_spec, shin, faces, p2f, out);
    }
}

// Round 3
// 353.788 us; speedup vs baseline: 1.0711x; 1.0166x over previous
//
#include <hip/hip_runtime.h>
#include <math.h>

#define SIGMA_C   1e-4f
#define GAMMA_C   1e-4f
#define ZNEAR_C   1.0f
#define ZFAR_C    100.0f
#define EPSB_C    1e-10f
// compile-time-folded reciprocals (exact constant folding; avoids 10-instr f32 divides)
#define INV_SIGMA  (1.0f / SIGMA_C)
#define INV_GAMMA  (1.0f / GAMMA_C)
#define INV_ZRANGE (1.0f / (ZFAR_C - ZNEAR_C))

static constexpr int N_ = 8, H_ = 512, W_ = 512, K_ = 4;
static constexpr int NPIX = N_ * H_ * W_;     // 2,097,152
static constexpr int NSMP = NPIX * K_;        // 8,388,608
static constexpr int F_ = 100000;
static constexpr int REC_U = 16;              // uints per record (64 B stride, 64B-aligned)
static constexpr size_t TABLE_BYTES = (size_t)F_ * REC_U * sizeof(unsigned int); // 6.4 MB
// blocks per batch for the sample kernel: (H*W*K)/256 = 4096 = 2^12
static_assert((H_ * W_ * K_) / 256 == 4096, "uniform-n derivation");

typedef float        fvec4 __attribute__((ext_vector_type(4)));
typedef float        fvec2 __attribute__((ext_vector_type(2)));
typedef unsigned int uvec4 __attribute__((ext_vector_type(4)));
typedef unsigned int uvec2 __attribute__((ext_vector_type(2)));
typedef _Float16     hvec2 __attribute__((ext_vector_type(2)));
// 12-byte vector with 4B alignment: emits global_load_dwordx3, never widens to 16B
typedef float        fvec3_ __attribute__((ext_vector_type(3)));
typedef fvec3_       fvec3 __attribute__((aligned(4)));

struct F3 { float x, y, z; };

__device__ __forceinline__ float ntf(const float* p) {
    return __builtin_nontemporal_load(p);
}
__device__ __forceinline__ fvec3_ ntf3(const float* p) {
    return __builtin_nontemporal_load(reinterpret_cast<const fvec3*>(p));
}
__device__ __forceinline__ unsigned int packh(float lo, float hi) {
    hvec2 h; h.x = (_Float16)lo; h.y = (_Float16)hi;
    return __builtin_bit_cast(unsigned int, h);
}
__device__ __forceinline__ hvec2 unpackh(unsigned int u) {
    return __builtin_bit_cast(hvec2, u);
}

// Quad (4-lane) cross-lane via DPP quad_perm — VALU pipe, no LDS round trip.
__device__ __forceinline__ float qxor1(float v) {   // quad_perm:[1,0,3,2] = 0xB1
    return __builtin_bit_cast(float, __builtin_amdgcn_update_dpp(
        0, __builtin_bit_cast(int, v), 0xB1, 0xF, 0xF, true));
}
__device__ __forceinline__ float qxor2(float v) {   // quad_perm:[2,3,0,1] = 0x4E
    return __builtin_bit_cast(float, __builtin_amdgcn_update_dpp(
        0, __builtin_bit_cast(int, v), 0x4E, 0xF, 0xF, true));
}
// quad broadcasts (float): every lane of the quad reads lane {0,1,2}
__device__ __forceinline__ float qbc0(float v) {    // quad_perm:[0,0,0,0] = 0x00
    return __builtin_bit_cast(float, __builtin_amdgcn_update_dpp(
        0, __builtin_bit_cast(int, v), 0x00, 0xF, 0xF, true));
}
__device__ __forceinline__ float qbc1(float v) {    // quad_perm:[1,1,1,1] = 0x55
    return __builtin_bit_cast(float, __builtin_amdgcn_update_dpp(
        0, __builtin_bit_cast(int, v), 0x55, 0xF, 0xF, true));
}
__device__ __forceinline__ float qbc2(float v) {    // quad_perm:[2,2,2,2] = 0xAA
    return __builtin_bit_cast(float, __builtin_amdgcn_update_dpp(
        0, __builtin_bit_cast(int, v), 0xAA, 0xF, 0xF, true));
}
// quad broadcasts (int) — used to share the quad's 4 face ids for cooperative gather
__device__ __forceinline__ int qbci0(int v) {
    return __builtin_amdgcn_update_dpp(0, v, 0x00, 0xF, 0xF, true);
}
__device__ __forceinline__ int qbci1(int v) {
    return __builtin_amdgcn_update_dpp(0, v, 0x55, 0xF, 0xF, true);
}
__device__ __forceinline__ int qbci2(int v) {
    return __builtin_amdgcn_update_dpp(0, v, 0xAA, 0xF, 0xF, true);
}
__device__ __forceinline__ int qbci3(int v) {
    return __builtin_amdgcn_update_dpp(0, v, 0xFF, 0xF, 0xF, true);
}

// Fast approx helpers (v_rcp_f32 / v_rsq_f32: ~1 ulp; fine vs fp16-vert error path)
__device__ __forceinline__ float frcp(float x)  { return __builtin_amdgcn_rcpf(x); }
__device__ __forceinline__ float frsq(float x)  { return __builtin_amdgcn_rsqf(x); }

// ---------------- Phase 1: pack faces -> 64B records --------------------
// rec (16 dwords): [n0.x n0.y n0.z n1.x][n1.y n1.z n2.x n2.y]
//                  [n2.z h(v0x,v0y) h(v0z,v1x) h(v1y,v1z)][h(v2x,v2y) h(v2z,0) pad pad]
// normals fp32 (1/|pn| + ^shininess amplification forbids compression);
// verts fp16 (benign error path). 1 cache line, 1 line-visit per sample (cooperative).
__global__ __launch_bounds__(256) void build_face_table(
    const float* __restrict__ verts,
    const float* __restrict__ vnorm,
    const int*   __restrict__ faces,
    unsigned int* __restrict__ table)
{
    const int f = blockIdx.x * 256 + threadIdx.x;
    if (f >= F_) return;
    const int i0 = faces[3*f+0], i1 = faces[3*f+1], i2 = faces[3*f+2];
    const F3 a = reinterpret_cast<const F3*>(verts)[i0];
    const F3 b = reinterpret_cast<const F3*>(verts)[i1];
    const F3 c = reinterpret_cast<const F3*>(verts)[i2];
    const F3 p = reinterpret_cast<const F3*>(vnorm)[i0];
    const F3 q = reinterpret_cast<const F3*>(vnorm)[i1];
    const F3 r = reinterpret_cast<const F3*>(vnorm)[i2];
    unsigned int* o = table + (size_t)f * REC_U;
    fvec4 A; A.x = p.x; A.y = p.y; A.z = p.z; A.w = q.x;
    fvec4 B; B.x = q.y; B.y = q.z; B.z = r.x; B.w = r.y;
    uvec4 C; C.x = __builtin_bit_cast(unsigned int, r.z);
    C.y = packh(a.x, a.y); C.z = packh(a.z, b.x); C.w = packh(b.y, b.z);
    uvec4 D; D.x = packh(c.x, c.y); D.y = packh(c.z, 0.0f); D.z = 0u; D.w = 0u;
    *reinterpret_cast<fvec4*>(o + 0)  = A;
    *reinterpret_cast<fvec4*>(o + 4)  = B;
    *reinterpret_cast<uvec4*>(o + 8)  = C;
    *reinterpret_cast<uvec4*>(o + 12) = D;   // full-width store; pad dwords unused
}

// ---------------- Phase 2: one thread per (pixel, sample) ----------------
// Cooperative quad gather: instruction i loads record of the quad's sample i,
// lane k fetching chunk k -> ONE cache line per quad per instruction (64 line
// visits/wave instead of 256). Un-transpose via a small LDS scratch:
// 80B record stride keeps ds_read/ds_write_b128 16B-aligned and spreads the
// 64 lanes' 16B slots uniformly over all 8 bank-quads for both patterns.
__global__ __launch_bounds__(256) void soft_phong_sample(
    const unsigned int* __restrict__ table,
    const float* __restrict__ bary,
    const float* __restrict__ zbuf,
    const float* __restrict__ dists,
    const float* __restrict__ texels,
    const float* __restrict__ vis,
    const float* __restrict__ l_loc,
    const float* __restrict__ l_amb,
    const float* __restrict__ l_dif,
    const float* __restrict__ l_spec,
    const float* __restrict__ cam,
    const float* __restrict__ m_amb,
    const float* __restrict__ m_dif,
    const float* __restrict__ m_spec,
    const float* __restrict__ shininess,
    const int*   __restrict__ p2f,
    float* __restrict__ out)
{
    __shared__ unsigned int xlds[64 * 80];         // 64 quads x 4 records x 80B = 20 KB

    const int tid = threadIdx.x;
    const int s = blockIdx.x * 256 + tid;          // sample index = 4*pixel + k
    const int p = s >> 2;
    const int k = tid & 3;
    const int tq = tid >> 2;                       // quad id within block (0..63)
    // batch index derived from blockIdx only -> provably wave-uniform -> the 14
    // per-batch loads below become SMEM s_load on the constant cache (not VMEM)
    const int n = blockIdx.x >> 12;                // 4096 blocks per batch

    // face index first -> gather chain starts ASAP
    const int  f0   = __builtin_nontemporal_load(p2f + s);
    const bool live = f0 >= 0;
    const int  f    = live ? f0 : 0;

    // quad's 4 face ids in every lane (DPP broadcast; all lanes active here)
    const int fb0 = qbci0(f), fb1 = qbci1(f), fb2 = qbci2(f), fb3 = qbci3(f);

    // cooperative gathers: instr i -> record fb_i, lane k -> chunk k (dwordx4)
    const uvec4 r0 = *reinterpret_cast<const uvec4*>(table + (size_t)fb0 * REC_U + 4*k);
    const uvec4 r1 = *reinterpret_cast<const uvec4*>(table + (size_t)fb1 * REC_U + 4*k);
    const uvec4 r2 = *reinterpret_cast<const uvec4*>(table + (size_t)fb2 * REC_U + 4*k);
    const uvec4 r3 = *reinterpret_cast<const uvec4*>(table + (size_t)fb3 * REC_U + 4*k);

    // streaming loads issued while gathers are in flight
    const float  zb = ntf(zbuf + s);
    const float  dd = ntf(dists + s);
    const fvec3_ bv = ntf3(bary + 3*s);
    const fvec3_ tv = ntf3(texels + 3*s);
    const int   kv = (k < 3) ? k : 2;
    const float lv = vis[3*p + kv];

    // LDS transpose: write record-major (record i at i*20 dw), read lane-major
    unsigned int* qb = xlds + tq * 80;
    *reinterpret_cast<uvec4*>(qb + 0*20 + 4*k) = r0;
    *reinterpret_cast<uvec4*>(qb + 1*20 + 4*k) = r1;
    *reinterpret_cast<uvec4*>(qb + 2*20 + 4*k) = r2;
    *reinterpret_cast<uvec4*>(qb + 3*20 + 4*k) = r3;
    // same-wave producer/consumer: compiler inserts lgkmcnt, no barrier needed
    const fvec4 A = *reinterpret_cast<const fvec4*>(qb + k*20 + 0);
    const fvec4 B = *reinterpret_cast<const fvec4*>(qb + k*20 + 4);
    const uvec4 C = *reinterpret_cast<const uvec4*>(qb + k*20 + 8);
    const uvec2 D = *reinterpret_cast<const uvec2*>(qb + k*20 + 12);

    const float b0 = bv.x, b1 = bv.y, b2 = bv.z;
    const float t0 = tv.x, t1 = tv.y, t2 = tv.z;
    // vis channels reconstructed from one dword/lane via quad DPP broadcasts
    const float vR = qbc0(lv), vG = qbc1(lv), vB = qbc2(lv);

    // per-batch uniforms (scalarized -> s_load + SALU)
    const float llx = l_loc[3*n+0], lly = l_loc[3*n+1], llz = l_loc[3*n+2];
    const float ccx = cam[3*n+0],   ccy = cam[3*n+1],   ccz = cam[3*n+2];
    const float ambR = m_amb[3*n+0]*l_amb[3*n+0];
    const float ambG = m_amb[3*n+1]*l_amb[3*n+1];
    const float ambB = m_amb[3*n+2]*l_amb[3*n+2];
    const float kdR  = m_dif[3*n+0]*l_dif[3*n+0];
    const float kdG  = m_dif[3*n+1]*l_dif[3*n+1];
    const float kdB  = m_dif[3*n+2]*l_dif[3*n+2];
    const float ksR  = m_spec[3*n+0]*l_spec[3*n+0];
    const float ksG  = m_spec[3*n+1]*l_spec[3*n+1];
    const float ksB  = m_spec[3*n+2]*l_spec[3*n+2];
    const float shin = shininess[n];

    // ---- unpack record ----
    const float n2z = __builtin_bit_cast(float, C.x);
    const hvec2 h0 = unpackh(C.y);   // v0x v0y
    const hvec2 h1 = unpackh(C.z);   // v0z v1x
    const hvec2 h2 = unpackh(C.w);   // v1y v1z
    const hvec2 h3 = unpackh(D.x);   // v2x v2y
    const hvec2 h4 = unpackh(D.y);   // v2z -
    const float v0x = (float)h0.x, v0y = (float)h0.y, v0z = (float)h1.x;
    const float v1x = (float)h1.y, v1y = (float)h2.x, v1z = (float)h2.y;
    const float v2x = (float)h3.x, v2y = (float)h3.y, v2z = (float)h4.x;

    // ---- shade this sample ----
    const float pcx = b0*v0x + b1*v1x + b2*v2x;
    const float pcy = b0*v0y + b1*v1y + b2*v2y;
    const float pcz = b0*v0z + b1*v1z + b2*v2z;

    const float pnx = b0*A.x + b1*A.w + b2*B.z;
    const float pny = b0*A.y + b1*B.x + b2*B.w;
    const float pnz = b0*A.z + b1*B.y + b2*n2z;

    // rsqrt on squared length == 1/max(|pn|,1e-6) for |pn| > 1e-6 (guard via 1e-12 on sq)
    const float inl = frsq(fmaxf(pnx*pnx + pny*pny + pnz*pnz, 1e-12f));
    const float nx = pnx*inl, ny = pny*inl, nz = pnz*inl;

    float dx = llx - pcx, dy = lly - pcy, dz = llz - pcz;
    const float idl = frsq(fmaxf(dx*dx + dy*dy + dz*dz, 1e-12f));
    dx *= idl; dy *= idl; dz *= idl;

    const float cosang = nx*dx + ny*dy + nz*dz;
    const float rcos   = fmaxf(cosang, 0.0f);

    const float rx = 2.0f*cosang*nx - dx;
    const float ry = 2.0f*cosang*ny - dy;
    const float rz = 2.0f*cosang*nz - dz;

    float vx = ccx - pcx, vy = ccy - pcy, vz = ccz - pcz;
    const float ivl = frsq(fmaxf(vx*vx + vy*vy + vz*vz, 1e-12f));
    vx *= ivl; vy *= ivl; vz *= ivl;

    const float sdot = vx*rx + vy*ry + vz*rz;
    const float spec_cos = (cosang > 0.0f) ? fmaxf(sdot, 0.0f) : 0.0f;
    const float sp = (spec_cos > 0.0f) ? exp2f(shin * log2f(spec_cos)) : 0.0f;

    const float colR = (ambR + kdR*rcos*vR) * t0 + ksR*sp;
    const float colG = (ambG + kdG*rcos*vG) * t1 + ksG*sp;
    const float colB = (ambB + kdB*rcos*vB) * t2 + ksB*sp;

    const float prob = live ? frcp(1.0f + __expf(dd * INV_SIGMA)) : 0.0f;
    const float zinv = live ? (ZFAR_C - zb) * INV_ZRANGE : 0.0f;

    // ---- quad (4-lane) blend reduction via DPP butterflies (no LDS) ----
    float zmax = zinv;
    zmax = fmaxf(zmax, qxor1(zmax));
    zmax = fmaxf(zmax, qxor2(zmax));
    zmax = fmaxf(zmax, EPSB_C);

    const float w = prob * __expf((zinv - zmax) * INV_GAMMA);
    float aw = w, aR = w*colR, aG = w*colG, aB = w*colB, kp = 1.0f - prob;

    aw += qxor1(aw);  aR += qxor1(aR);
    aG += qxor1(aG);  aB += qxor1(aB);
    kp *= qxor1(kp);
    aw += qxor2(aw);  aR += qxor2(aR);
    aG += qxor2(aG);  aB += qxor2(aB);
    kp *= qxor2(kp);

    const float delta = __expf((EPSB_C - zmax) * INV_GAMMA);
    const float inv   = frcp(aw + delta);

    // lane k writes channel k -> out[4p+k] == out[s]; fully coalesced dwords
    float val;
    if      (k == 0) val = (aR + delta) * inv;
    else if (k == 1) val = (aG + delta) * inv;
    else if (k == 2) val = (aB + delta) * inv;
    else             val = 1.0f - kp;
    __builtin_nontemporal_store(val, out + s);
}

// ---------------- Fallback (direct per-pixel gather) --------------------
__global__ __launch_bounds__(256) void soft_phong_direct(
    const float* __restrict__ verts,
    const float* __restrict__ vnorm,
    const float* __restrict__ bary,
    const float* __restrict__ zbuf,
    const float* __restrict__ dists,
    const float* __restrict__ texels,
    const float* __restrict__ vis,
    const float* __restrict__ l_loc,
    const float* __restrict__ l_amb,
    const float* __restrict__ l_dif,
    const float* __restrict__ l_spec,
    const float* __restrict__ cam,
    const float* __restrict__ m_amb,
    const float* __restrict__ m_dif,
    const float* __restrict__ m_spec,
    const float* __restrict__ shininess,
    const int*   __restrict__ faces,
    const int*   __restrict__ p2f,
    float* __restrict__ out)
{
    const int p = blockIdx.x * 256 + threadIdx.x;
    const int n = p >> 18;
    struct I3 { int x, y, z; };
    const int fi[4] = {p2f[4*p+0], p2f[4*p+1], p2f[4*p+2], p2f[4*p+3]};
    I3 fidx[4];
#pragma unroll
    for (int k = 0; k < 4; ++k) {
        const int f = (fi[k] >= 0) ? fi[k] : 0;
        fidx[k] = reinterpret_cast<const I3*>(faces)[f];
    }
    F3 vp[4][3], vn[4][3];
#pragma unroll
    for (int k = 0; k < 4; ++k) {
        const int i0 = fidx[k].x, i1 = fidx[k].y, i2 = fidx[k].z;
        vp[k][0] = reinterpret_cast<const F3*>(verts)[i0];
        vp[k][1] = reinterpret_cast<const F3*>(verts)[i1];
        vp[k][2] = reinterpret_cast<const F3*>(verts)[i2];
        vn[k][0] = reinterpret_cast<const F3*>(vnorm)[i0];
        vn[k][1] = reinterpret_cast<const F3*>(vnorm)[i1];
        vn[k][2] = reinterpret_cast<const F3*>(vnorm)[i2];
    }
    const float llx = l_loc[3*n+0], lly = l_loc[3*n+1], llz = l_loc[3*n+2];
    const float ccx = cam[3*n+0],   ccy = cam[3*n+1],   ccz = cam[3*n+2];
    const float ambR = m_amb[3*n+0]*l_amb[3*n+0];
    const float ambG = m_amb[3*n+1]*l_amb[3*n+1];
    const float ambB = m_amb[3*n+2]*l_amb[3*n+2];
    const float kdR  = m_dif[3*n+0]*l_dif[3*n+0];
    const float kdG  = m_dif[3*n+1]*l_dif[3*n+1];
    const float kdB  = m_dif[3*n+2]*l_dif[3*n+2];
    const float ksR  = m_spec[3*n+0]*l_spec[3*n+0];
    const float ksG  = m_spec[3*n+1]*l_spec[3*n+1];
    const float ksB  = m_spec[3*n+2]*l_spec[3*n+2];
    const float shin = shininess[n];
    float colR[4], colG[4], colB[4], prob[4], zinv[4];
    float zmax = EPSB_C;
#pragma unroll
    for (int k = 0; k < 4; ++k) {
        const bool live = fi[k] >= 0;
        const float b0 = bary[12*p+3*k+0], b1 = bary[12*p+3*k+1], b2 = bary[12*p+3*k+2];
        const float pcx = b0*vp[k][0].x + b1*vp[k][1].x + b2*vp[k][2].x;
        const float pcy = b0*vp[k][0].y + b1*vp[k][1].y + b2*vp[k][2].y;
        const float pcz = b0*vp[k][0].z + b1*vp[k][1].z + b2*vp[k][2].z;
        const float pnx = b0*vn[k][0].x + b1*vn[k][1].x + b2*vn[k][2].x;
        const float pny = b0*vn[k][0].y + b1*vn[k][1].y + b2*vn[k][2].y;
        const float pnz = b0*vn[k][0].z + b1*vn[k][1].z + b2*vn[k][2].z;
        const float inl = frsq(fmaxf(pnx*pnx + pny*pny + pnz*pnz, 1e-12f));
        const float nx = pnx*inl, ny = pny*inl, nz = pnz*inl;
        float dx = llx - pcx, dy = lly - pcy, dz = llz - pcz;
        const float idl = frsq(fmaxf(dx*dx + dy*dy + dz*dz, 1e-12f));
        dx *= idl; dy *= idl; dz *= idl;
        const float cosang = nx*dx + ny*dy + nz*dz;
        const float rcos   = fmaxf(cosang, 0.0f);
        const float rx = 2.0f*cosang*nx - dx;
        const float ry = 2.0f*cosang*ny - dy;
        const float rz = 2.0f*cosang*nz - dz;
        float vx = ccx - pcx, vy = ccy - pcy, vz = ccz - pcz;
        const float ivl = frsq(fmaxf(vx*vx + vy*vy + vz*vz, 1e-12f));
        vx *= ivl; vy *= ivl; vz *= ivl;
        const float sdot = vx*rx + vy*ry + vz*rz;
        const float spec_cos = (cosang > 0.0f) ? fmaxf(sdot, 0.0f) : 0.0f;
        const float sp = (spec_cos > 0.0f) ? exp2f(shin * log2f(spec_cos)) : 0.0f;
        const float vRl = vis[3*p+0], vGl = vis[3*p+1], vBl = vis[3*p+2];
        colR[k] = (ambR + kdR*rcos*vRl) * texels[12*p+3*k+0] + ksR*sp;
        colG[k] = (ambG + kdG*rcos*vGl) * texels[12*p+3*k+1] + ksG*sp;
        colB[k] = (ambB + kdB*rcos*vBl) * texels[12*p+3*k+2] + ksB*sp;
        prob[k] = live ? frcp(1.0f + __expf(dists[4*p+k] * INV_SIGMA)) : 0.0f;
        zinv[k] = live ? (ZFAR_C - zbuf[4*p+k]) * INV_ZRANGE : 0.0f;
        zmax = fmaxf(zmax, zinv[k]);
    }
    const float delta = __expf((EPSB_C - zmax) * INV_GAMMA);
    float denom = delta, accR = delta, accG = delta, accB = delta, keep = 1.0f;
#pragma unroll
    for (int k = 0; k < 4; ++k) {
        const float w = prob[k] * __expf((zinv[k] - zmax) * INV_GAMMA);
        denom += w; accR += w*colR[k]; accG += w*colG[k]; accB += w*colB[k];
        keep *= (1.0f - prob[k]);
    }
    const float inv = frcp(denom);
    out[4*p+0] = accR*inv; out[4*p+1] = accG*inv; out[4*p+2] = accB*inv; out[4*p+3] = 1.0f - keep;
}

extern "C" void kernel_launch(void* const* d_in, const int* in_sizes, int n_in,
                              void* d_out, int out_size, void* d_ws, size_t ws_size,
                              hipStream_t stream) {
    const float* verts   = (const float*)d_in[0];
    const float* vnorm   = (const float*)d_in[1];
    const float* bary    = (const float*)d_in[2];
    const float* zbuf    = (const float*)d_in[3];
    const float* dists   = (const float*)d_in[4];
    const float* texels  = (const float*)d_in[5];
    const float* vis     = (const float*)d_in[6];
    const float* l_loc   = (const float*)d_in[7];
    const float* l_amb   = (const float*)d_in[8];
    const float* l_dif   = (const float*)d_in[9];
    const float* l_spec  = (const float*)d_in[10];
    const float* cam     = (const float*)d_in[11];
    const float* m_amb   = (const float*)d_in[12];
    const float* m_dif   = (const float*)d_in[13];
    const float* m_spec  = (const float*)d_in[14];
    const float* shin    = (const float*)d_in[15];
    const int*   faces   = (const int*)d_in[16];
    const int*   p2f     = (const int*)d_in[17];
    float* out = (float*)d_out;

    if (ws_size >= TABLE_BYTES) {
        unsigned int* table = (unsigned int*)d_ws;
        build_face_table<<<(F_ + 255) / 256, 256, 0, stream>>>(verts, vnorm, faces, table);
        soft_phong_sample<<<NSMP / 256, 256, 0, stream>>>(
            table, bary, zbuf, dists, texels, vis,
            l_loc, l_amb, l_dif, l_spec, cam,
            m_amb, m_dif, m_spec, shin, p2f, out);
    } else {
        soft_phong_direct<<<NPIX / 256, 256, 0, stream>>>(
            verts, vnorm, bary, zbuf, dists, texels, vis,
            l_loc, l_amb, l_dif, l_spec, cam,
            m_amb, m_dif, m_spec, shin, faces, p2f, out);
    }
}